// Round 14
// baseline (548.316 us; speedup 1.0000x reference)
//
#include <hip/hip_runtime.h>
#include <hip/hip_bf16.h>

// Problem constants (GATModule: N=8192, IN=128, OUT=64, H=4) — fp32 inputs/output.
#define NN   8192
#define IND  128
#define OUTD 64
#define NH   4
#define NEG_SLOPE 0.2f
#define BN_EPS 1e-5f

typedef __attribute__((ext_vector_type(8))) short bf16x8;   // MFMA A/B frag (8 bf16)
typedef __attribute__((ext_vector_type(4))) float f32x4;    // MFMA C/D frag
typedef __attribute__((ext_vector_type(4))) int   i32x4;

static __device__ __forceinline__ short f2bf(float f) {
    union { float f; unsigned u; } v; v.f = f;
    return (short)((v.u + 0x8000u) >> 16);
}

// async global->LDS, 16 B/lane. g is per-lane (already includes lane offset), lbase is
// wave-uniform; HW writes lane i at lbase + 16*i (matches g = base + lane*8 shorts).
static __device__ __forceinline__ void stage16(const short* g, short* lbase, int lane) {
#if defined(__has_builtin) && __has_builtin(__builtin_amdgcn_global_load_lds)
    __builtin_amdgcn_global_load_lds((const __attribute__((address_space(1))) void*)g,
                                     (__attribute__((address_space(3))) void*)lbase,
                                     16, 0, 0);
#else
    *(bf16x8*)(lbase + lane * 8) = *(const bf16x8*)g;
#endif
}

// ---------------- K0: repack W[h][k][o] fp32 -> WB bf16 [h][k/8][o][k%8] (B-frag) ----------
__global__ __launch_bounds__(256) void k0_repackW(const float* __restrict__ W,
                                                  short* __restrict__ WB) {
    int tid = blockIdx.x * 256 + threadIdx.x;      // 0..32767
    int o = tid & 63, i = (tid >> 6) & 127, h = tid >> 13;
    WB[((h * 16 + (i >> 3)) * 64 + o) * 8 + (i & 7)] = f2bf(W[(h * 128 + i) * 64 + o]);
}

// ---------------- K1: h = x@W per head (MFMA); store hB bf16 + tables ----------------------
// Tables: t_Ri = exp(-0.8 ei), t_E1j = exp(ej), t_E2j = exp(0.2 ej).
// Row-rescaled P via the max identity: exp(leakyrelu(ei+ej))/exp(ei) = max(E1j, Ri*E2j).
__global__ __launch_bounds__(256) void k1_feat(const float* __restrict__ x,
                                               const short* __restrict__ WB,
                                               const float* __restrict__ a_i,
                                               const float* __restrict__ a_j,
                                               short* __restrict__ hB,
                                               float* __restrict__ t_Ri,
                                               float* __restrict__ t_E1j, float* __restrict__ t_E2j) {
    int w = threadIdx.x >> 6;        // head
    int l = threadIdx.x & 63;
    int quad = l >> 4, lx = l & 15;
    int rb = blockIdx.x;             // 16-row block

    f32x4 acc[4] = {};               // 4 o-tiles of 16
#pragma unroll
    for (int ks = 0; ks < 4; ++ks) { // K=128 in 4 steps of 32
        const float* xp = x + (rb * 16 + lx) * IND + ks * 32 + quad * 8;
        f32x4 xa = *(const f32x4*)xp;
        f32x4 xb = *(const f32x4*)(xp + 4);
        bf16x8 af;
#pragma unroll
        for (int j = 0; j < 4; ++j) { af[j] = f2bf(xa[j]); af[4 + j] = f2bf(xb[j]); }
#pragma unroll
        for (int ot = 0; ot < 4; ++ot) {
            bf16x8 bf = *(const bf16x8*)(WB + ((w * 16 + ks * 4 + quad) * 64 + ot * 16 + lx) * 8);
            acc[ot] = __builtin_amdgcn_mfma_f32_16x16x32_bf16(af, bf, acc[ot], 0, 0, 0);
        }
    }
    float aiv[4], ajv[4];
#pragma unroll
    for (int ot = 0; ot < 4; ++ot) {
        aiv[ot] = a_i[w * 64 + ot * 16 + lx];
        ajv[ot] = a_j[w * 64 + ot * 16 + lx];
    }
#pragma unroll
    for (int reg = 0; reg < 4; ++reg) {
        int row = rb * 16 + quad * 4 + reg;       // C-layout: row=quad*4+reg, col=lane&15
        float ei = 0.f, ej = 0.f;
#pragma unroll
        for (int ot = 0; ot < 4; ++ot) {
            float hv = acc[ot][reg];
            ei += hv * aiv[ot];
            ej += hv * ajv[ot];
        }
#pragma unroll
        for (int m = 1; m <= 8; m <<= 1) {        // reduce over the 16 lanes of this row
            ei += __shfl_xor(ei, m, 64);
            ej += __shfl_xor(ej, m, 64);
        }
        if (lx == reg) {
            t_Ri [w * NN + row] = expf(-0.8f * ei);
            t_E1j[w * NN + row] = expf(ej);
            t_E2j[w * NN + row] = expf(NEG_SLOPE * ej);
        }
#pragma unroll
        for (int ot = 0; ot < 4; ++ot) {          // hB[h][n/8][o][n%8]
            int o = ot * 16 + lx;
            hB[((w * 1024 + (row >> 3)) * 64 + o) * 8 + (row & 7)] = f2bf(acc[ot][reg]);
        }
    }
}

// ---------------- K2: attention (LDS mask + async hB double-buffer, m97-style) -------------
// grid 512 = 128 rowblocks(64) x 4 K-splits(2048 cols); block 256 = 4 waves, wave w = head.
// Per kt: hB kt-chunk (4 KB/head, contiguous) DMA'd via global_load_lds into buf[np] while
// computing from buf[pp]; __syncthreads() each kt enforces the prefetch distance in HW.
// Tables + mask bytes in explicit ping-pong register sets (unroll-2, no rotate movs).
__global__ __launch_bounds__(256) void k2_attn(const int* __restrict__ adj,
                                               const short* __restrict__ hB,
                                               const float* __restrict__ t_Ri,
                                               const float* __restrict__ t_E1j,
                                               const float* __restrict__ t_E2j,
                                               float* __restrict__ num,
                                               float* __restrict__ Lsum) {
    __shared__ short shbuf[2][8192];           // 2 x 16 KB hB chunks (4 heads x 4 KB)
    __shared__ unsigned char smask[64 * 260];  // 16.6 KB bit-per-edge slice mask
    int tid = threadIdx.x;
    int w = tid >> 6;                          // head
    int l = tid & 63;
    int quad = l >> 4, lx = l & 15;
    int rb = blockIdx.x >> 2, ks = blockIdx.x & 3;
    int rowbase = rb * 64;
    int tb = w * NN;
    int k0 = ks * 2048;

    // hB chunk base (shorts): chunk(kt) = chunkbase + kt*2048, 4 KB contiguous per head
    const short* chunkbase = hB + (size_t)(w * 1024 + (k0 >> 3)) * 512;

    f32x4 te1[2][2], te2[2][2];                // ping-pong table registers
    // ---- async-stage buf0 (kt=0) + kt=0 tables: overlaps the adj sweep below ----
#pragma unroll
    for (int inst = 0; inst < 4; ++inst)
        stage16(chunkbase + inst * 512 + l * 8, &shbuf[0][w * 2048 + inst * 512], l);
    {
        int kb = k0 + quad * 8;
        te1[0][0] = *(const f32x4*)(t_E1j + tb + kb);
        te1[0][1] = *(const f32x4*)(t_E1j + tb + kb + 4);
        te2[0][0] = *(const f32x4*)(t_E2j + tb + kb);
        te2[0][1] = *(const f32x4*)(t_E2j + tb + kb + 4);
    }

    // ---- Phase 1: stage adj slice (64 x 2048) -> LDS bitmask, coalesced ----
    {
        int kc = tid * 8;                      // this thread's 8-int k slot (0..2040)
#pragma unroll 4
        for (int i = 0; i < 64; ++i) {
            const int* ap = adj + (size_t)(rowbase + i) * NN + k0 + kc;
            i32x4 a0 = *(const i32x4*)ap;
            i32x4 a1 = *(const i32x4*)(ap + 4);
            unsigned m = 0;
#pragma unroll
            for (int j = 0; j < 4; ++j) {
                m |= (a0[j] ? 1u : 0u) << j;
                m |= (a1[j] ? 1u : 0u) << (4 + j);
            }
            smask[i * 260 + tid] = (unsigned char)m;   // bit j of byte t = adj[i][t*8+j]
        }
    }
    __syncthreads();                           // drains adj stores AND buf0 DMA

    float Riv[4];
    int mrow[4];
#pragma unroll
    for (int r = 0; r < 4; ++r) {
        Riv[r] = t_Ri[tb + rowbase + r * 16 + lx];   // A row: lane&15
        mrow[r] = (r * 16 + lx) * 260 + quad;        // + kt*4 per iteration
    }
    int pm[2][4];
#pragma unroll
    for (int r = 0; r < 4; ++r) pm[0][r] = smask[mrow[r]];   // kt=0 mask bytes

    bf16x8 onesf;                              // B = all ones -> MFMA row sums
#pragma unroll
    for (int j = 0; j < 8; ++j) onesf[j] = (short)0x3F80;

    f32x4 acc[4][4] = {};                      // [m-tile][o-tile]
    f32x4 accL[4] = {};                        // row-sum accumulators

#pragma unroll 2
    for (int kt = 0; kt < 64; ++kt) {
        int pp = kt & 1, np = pp ^ 1;
        int ktn = (kt + 1) & 63;               // wrap: last-iter re-stage is harmless

        // ---- issue next iteration's loads (async DMA + tables + mask bytes) ----
#pragma unroll
        for (int inst = 0; inst < 4; ++inst)
            stage16(chunkbase + ktn * 2048 + inst * 512 + l * 8,
                    &shbuf[np][w * 2048 + inst * 512], l);
        int kbn = k0 + ktn * 32 + quad * 8;
        te1[np][0] = *(const f32x4*)(t_E1j + tb + kbn);
        te1[np][1] = *(const f32x4*)(t_E1j + tb + kbn + 4);
        te2[np][0] = *(const f32x4*)(t_E2j + tb + kbn);
        te2[np][1] = *(const f32x4*)(t_E2j + tb + kbn + 4);
#pragma unroll
        for (int r = 0; r < 4; ++r) pm[np][r] = smask[mrow[r] + ktn * 4];

        // ---- compute current kt from LDS buf[pp] + register tables ----
        bf16x8 bfrag[4];
#pragma unroll
        for (int ot = 0; ot < 4; ++ot)
            bfrag[ot] = *(const bf16x8*)&shbuf[pp][w * 2048 + (quad * 64 + ot * 16 + lx) * 8];

        bf16x8 afr[4];
#pragma unroll
        for (int r = 0; r < 4; ++r) {
            int mc = pm[pp][r];
            union { i32x4 i; bf16x8 b; } af;
#pragma unroll
            for (int jj = 0; jj < 4; ++jj) {   // two elements per iter -> packed bf16
                int j0 = 2 * jj, j1 = 2 * jj + 1;
                float e1A = (j0 < 4) ? te1[pp][0][j0] : te1[pp][1][j0 - 4];
                float e1B = (j1 < 4) ? te1[pp][0][j1] : te1[pp][1][j1 - 4];
                float e2A = (j0 < 4) ? te2[pp][0][j0] : te2[pp][1][j0 - 4];
                float e2B = (j1 < 4) ? te2[pp][0][j1] : te2[pp][1][j1 - 4];
                float p0 = fmaxf(e1A, Riv[r] * e2A);     // = exp(leakyrelu(s))/exp(ei)
                float p1 = fmaxf(e1B, Riv[r] * e2B);
                p0 = (mc & (1 << j0)) ? p0 : 0.0f;       // adjacency mask bit
                p1 = (mc & (1 << j1)) ? p1 : 0.0f;
                af.i[jj] = (int)__builtin_amdgcn_perm(__float_as_uint(p1),
                                                      __float_as_uint(p0),
                                                      0x07060302); // [p1.hi16|p0.hi16] trunc
            }
            afr[r] = af.b;
        }
#pragma unroll
        for (int r = 0; r < 4; ++r)            // row sums on the MFMA pipe (B = ones)
            accL[r] = __builtin_amdgcn_mfma_f32_16x16x32_bf16(afr[r], onesf, accL[r], 0, 0, 0);
#pragma unroll
        for (int r = 0; r < 4; ++r)
#pragma unroll
            for (int ot = 0; ot < 4; ++ot)
                acc[r][ot] = __builtin_amdgcn_mfma_f32_16x16x32_bf16(afr[r], bfrag[ot], acc[r][ot], 0, 0, 0);

        __syncthreads();                       // buf[np] staged; buf[pp] free for re-stage
    }

    // softmax denominators: accL[r][reg] holds rowsum(row=quad*4+reg) in every col lane
#pragma unroll
    for (int r = 0; r < 4; ++r)
        if (lx == 0)
#pragma unroll
            for (int reg = 0; reg < 4; ++reg)
                atomicAdd(&Lsum[w * NN + rowbase + r * 16 + quad * 4 + reg], accL[r][reg]);
    // numerator: atomic combine across the 4 K-splits
#pragma unroll
    for (int r = 0; r < 4; ++r)
#pragma unroll
        for (int ot = 0; ot < 4; ++ot)
#pragma unroll
            for (int reg = 0; reg < 4; ++reg) {
                int row = rowbase + r * 16 + quad * 4 + reg;    // C/D: row=quad*4+reg
                atomicAdd(&num[row * 256 + w * 64 + ot * 16 + lx], acc[r][ot][reg]);
            }
}

// ---------------- K3: BN partial stats only (no val write; k5 re-divides) ------------------
// grid 1024 blocks x 8 rows; thread t = column c (h*64+o)
__global__ __launch_bounds__(256) void k3_stats(const float* __restrict__ num,
                                                const float* __restrict__ Lsum,
                                                float* __restrict__ stats) {
    int c = threadIdx.x;
    int h = c >> 6;
    float s = 0.f, s2 = 0.f;
#pragma unroll
    for (int rr = 0; rr < 8; ++rr) {
        int row = blockIdx.x * 8 + rr;
        float val = num[row * 256 + c] / Lsum[h * NN + row];
        s += val; s2 += val * val;
    }
    atomicAdd(&stats[c], s);
    atomicAdd(&stats[c + 256], s2);
}

// ---------------- K5: BN finalize (LDS) + divide + apply + ReLU -> fp32 out ----------------
__global__ __launch_bounds__(256) void k5_apply(const float* __restrict__ num,
                                                const float* __restrict__ Lsum,
                                                const float* __restrict__ stats,
                                                const float* __restrict__ gamma,
                                                const float* __restrict__ beta,
                                                float* __restrict__ out) {
    __shared__ float sbnp[512];
    int c = threadIdx.x;
    float mean = stats[c] * (1.0f / NN);
    float var  = stats[c + 256] * (1.0f / NN) - mean * mean;
    float sc = gamma[c] * rsqrtf(var + BN_EPS);
    sbnp[c] = sc;
    sbnp[c + 256] = beta[c] - mean * sc;
    __syncthreads();

    int g = blockIdx.x * 256 + threadIdx.x;        // float4 index, 524288 total
    f32x4 v = *(const f32x4*)(num + (size_t)g * 4);
    int cb = (g * 4) & 255;
    int row = g >> 6;
    float rL = 1.0f / Lsum[(cb >> 6) * NN + row];
    f32x4 r;
#pragma unroll
    for (int j = 0; j < 4; ++j)
        r[j] = fmaxf((v[j] * rL) * sbnp[cb + j] + sbnp[256 + cb + j], 0.0f);
    *(f32x4*)(out + (size_t)g * 4) = r;
}

extern "C" void kernel_launch(void* const* d_in, const int* in_sizes, int n_in,
                              void* d_out, int out_size, void* d_ws, size_t ws_size,
                              hipStream_t stream) {
    (void)in_sizes; (void)n_in; (void)out_size; (void)ws_size;
    const float* x     = (const float*)d_in[0];
    const int*   adj   = (const int*)d_in[1];
    const float* W     = (const float*)d_in[2];
    const float* a_i   = (const float*)d_in[3];
    const float* a_j   = (const float*)d_in[4];
    const float* gamma = (const float*)d_in[5];
    const float* beta  = (const float*)d_in[6];
    float* out = (float*)d_out;

    char* ws = (char*)d_ws;
    // workspace layout (~13.2 MB). num|Lsum|stats contiguous -> single memset.
    short* WB    = (short*)(ws + 0);              //   64 KB (bf16 W, B-frag layout)
    short* hB    = (short*)(ws + 65536);          //    4 MB (bf16 h, B-frag layout)
    float* t_Ri  = (float*)(ws + 4259840);        // 3 x 128 KB tables
    float* t_E1j = t_Ri + 32768;
    float* t_E2j = t_Ri + 2 * 32768;
    float* num   = (float*)(ws + 4784128);        //    8 MB (numerator, atomic-combined)
    float* Lsum  = (float*)(ws + 13172736);       //  128 KB
    float* stats = (float*)(ws + 13303808);       //    2 KB (atomic accum)

    hipMemsetAsync(num, 0, 8388608 + 131072 + 2048, stream);  // num + Lsum + stats

    k0_repackW<<<dim3(128),  dim3(256), 0, stream>>>(W, WB);
    k1_feat   <<<dim3(512),  dim3(256), 0, stream>>>(x, WB, a_i, a_j, hB,
                                                     t_Ri, t_E1j, t_E2j);
    k2_attn   <<<dim3(512),  dim3(256), 0, stream>>>(adj, hB, t_Ri, t_E1j, t_E2j,
                                                     num, Lsum);
    k3_stats  <<<dim3(1024), dim3(256), 0, stream>>>(num, Lsum, stats);
    k5_apply  <<<dim3(2048), dim3(256), 0, stream>>>(num, Lsum, stats, gamma, beta, out);
}

// Round 15
// 478.804 us; speedup vs baseline: 1.1452x; 1.1452x over previous
//
#include <hip/hip_runtime.h>
#include <hip/hip_bf16.h>

// Problem constants (GATModule: N=8192, IN=128, OUT=64, H=4) — fp32 inputs/output.
#define NN   8192
#define IND  128
#define OUTD 64
#define NH   4
#define NEG_SLOPE 0.2f
#define BN_EPS 1e-5f

typedef __attribute__((ext_vector_type(8))) short bf16x8;   // MFMA A/B frag (8 bf16)
typedef __attribute__((ext_vector_type(4))) float f32x4;    // MFMA C/D frag
typedef __attribute__((ext_vector_type(4))) int   i32x4;

static __device__ __forceinline__ short f2bf(float f) {
    union { float f; unsigned u; } v; v.f = f;
    return (short)((v.u + 0x8000u) >> 16);
}

// ---------------- K0: repack W[h][k][o] fp32 -> WB bf16 [h][k/8][o][k%8] (B-frag) ----------
__global__ __launch_bounds__(256) void k0_repackW(const float* __restrict__ W,
                                                  short* __restrict__ WB) {
    int tid = blockIdx.x * 256 + threadIdx.x;      // 0..32767
    int o = tid & 63, i = (tid >> 6) & 127, h = tid >> 13;
    WB[((h * 16 + (i >> 3)) * 64 + o) * 8 + (i & 7)] = f2bf(W[(h * 128 + i) * 64 + o]);
}

// ---------------- K1: h = x@W per head (MFMA); store hB bf16 + tables ----------------------
// t_Ri = exp(-0.8 ei) fp32; tE12 packed word = [E2j=exp(0.2 ej) bf16 | E1j=exp(ej) bf16].
// Row-rescaled P via the max identity: exp(leakyrelu(ei+ej))/exp(ei) = max(E1j, Ri*E2j).
__global__ __launch_bounds__(256) void k1_feat(const float* __restrict__ x,
                                               const short* __restrict__ WB,
                                               const float* __restrict__ a_i,
                                               const float* __restrict__ a_j,
                                               short* __restrict__ hB,
                                               float* __restrict__ t_Ri,
                                               unsigned int* __restrict__ tE12) {
    int w = threadIdx.x >> 6;        // head
    int l = threadIdx.x & 63;
    int quad = l >> 4, lx = l & 15;
    int rb = blockIdx.x;             // 16-row block

    f32x4 acc[4] = {};               // 4 o-tiles of 16
#pragma unroll
    for (int ks = 0; ks < 4; ++ks) { // K=128 in 4 steps of 32
        const float* xp = x + (rb * 16 + lx) * IND + ks * 32 + quad * 8;
        f32x4 xa = *(const f32x4*)xp;
        f32x4 xb = *(const f32x4*)(xp + 4);
        bf16x8 af;
#pragma unroll
        for (int j = 0; j < 4; ++j) { af[j] = f2bf(xa[j]); af[4 + j] = f2bf(xb[j]); }
#pragma unroll
        for (int ot = 0; ot < 4; ++ot) {
            bf16x8 bf = *(const bf16x8*)(WB + ((w * 16 + ks * 4 + quad) * 64 + ot * 16 + lx) * 8);
            acc[ot] = __builtin_amdgcn_mfma_f32_16x16x32_bf16(af, bf, acc[ot], 0, 0, 0);
        }
    }
    float aiv[4], ajv[4];
#pragma unroll
    for (int ot = 0; ot < 4; ++ot) {
        aiv[ot] = a_i[w * 64 + ot * 16 + lx];
        ajv[ot] = a_j[w * 64 + ot * 16 + lx];
    }
#pragma unroll
    for (int reg = 0; reg < 4; ++reg) {
        int row = rb * 16 + quad * 4 + reg;       // C-layout: row=quad*4+reg, col=lane&15
        float ei = 0.f, ej = 0.f;
#pragma unroll
        for (int ot = 0; ot < 4; ++ot) {
            float hv = acc[ot][reg];
            ei += hv * aiv[ot];
            ej += hv * ajv[ot];
        }
#pragma unroll
        for (int m = 1; m <= 8; m <<= 1) {        // reduce over the 16 lanes of this row
            ei += __shfl_xor(ei, m, 64);
            ej += __shfl_xor(ej, m, 64);
        }
        if (lx == reg) {
            t_Ri[w * NN + row] = expf(-0.8f * ei);
            unsigned e1 = (unsigned)(unsigned short)f2bf(expf(ej));
            unsigned e2 = (unsigned)(unsigned short)f2bf(expf(NEG_SLOPE * ej));
            tE12[w * NN + row] = (e2 << 16) | e1;
        }
#pragma unroll
        for (int ot = 0; ot < 4; ++ot) {          // hB[h][n/8][o][n%8]
            int o = ot * 16 + lx;
            hB[((w * 1024 + (row >> 3)) * 64 + o) * 8 + (row & 7)] = f2bf(acc[ot][reg]);
        }
    }
}

// ---------------- K2: attention (LDS byte mask; packed bf16 tables; unroll-2) --------------
// grid 512 = 128 rowblocks(64) x 4 K-splits(2048 cols); block 256 = 4 waves, wave w = head.
// Round-11 skeleton (measured best). Per kt: ONE packed-table stream (2 x i32x4 = 32 B/lane,
// halved) unpacked once and shared by all 4 r; hB B-frags prefetched at distance 1;
// unroll-2 renames the prefetch ping-pong (no rotate movs) and doubles independent chains.
__global__ __launch_bounds__(256) void k2_attn(const int* __restrict__ adj,
                                               const short* __restrict__ hB,
                                               const float* __restrict__ t_Ri,
                                               const unsigned int* __restrict__ tE12,
                                               float* __restrict__ num,
                                               float* __restrict__ Lsum) {
    __shared__ unsigned char smask[64 * 260];  // 16.6 KB bit-per-edge slice mask
    int tid = threadIdx.x;
    int w = tid >> 6;                          // head
    int l = tid & 63;
    int quad = l >> 4, lx = l & 15;
    int rb = blockIdx.x >> 2, ks = blockIdx.x & 3;
    int rowbase = rb * 64;
    int tb = w * NN;
    int k0 = ks * 2048;

    // ---- Phase 1: stage adj slice (64 x 2048) -> LDS bitmask, coalesced ----
    {
        int kc = tid * 8;                      // this thread's 8-int k slot (0..2040)
#pragma unroll 4
        for (int i = 0; i < 64; ++i) {
            const int* ap = adj + (size_t)(rowbase + i) * NN + k0 + kc;
            i32x4 a0 = *(const i32x4*)ap;
            i32x4 a1 = *(const i32x4*)(ap + 4);
            unsigned m = 0;
#pragma unroll
            for (int j = 0; j < 4; ++j) {
                m |= (a0[j] ? 1u : 0u) << j;
                m |= (a1[j] ? 1u : 0u) << (4 + j);
            }
            smask[i * 260 + tid] = (unsigned char)m;   // bit j of byte t = adj[i][t*8+j]
        }
    }
    __syncthreads();

    float Riv[4];
    int mrow[4];                               // LDS mask row base per r
#pragma unroll
    for (int r = 0; r < 4; ++r) {
        Riv[r] = t_Ri[tb + rowbase + r * 16 + lx];   // A row: lane&15
        mrow[r] = (r * 16 + lx) * 260 + quad;        // + kt*4 per iteration
    }

    bf16x8 onesf;                              // B = all ones -> MFMA row sums
#pragma unroll
    for (int j = 0; j < 8; ++j) onesf[j] = (short)0x3F80;

    f32x4 acc[4][4] = {};                      // [m-tile][o-tile]
    f32x4 accL[4] = {};                        // row-sum accumulators
    // -------- distance-1 prefetch: packed table words + hB B-frags --------
    i32x4 pt0, pt1;
    bf16x8 pbf[4];
    {
        int kb = k0 + quad * 8;                // kt = 0
        pt0 = *(const i32x4*)(tE12 + tb + kb);
        pt1 = *(const i32x4*)(tE12 + tb + kb + 4);
#pragma unroll
        for (int ot = 0; ot < 4; ++ot)
            pbf[ot] = *(const bf16x8*)(hB + ((w * 1024 + (kb >> 3)) * 64 + ot * 16 + lx) * 8);
    }

#pragma unroll 2
    for (int kt = 0; kt < 64; ++kt) {
        // rotate: current <- prefetched (unroll-2 renames these, no movs)
        i32x4 t0 = pt0, t1 = pt1;
        bf16x8 bfrag[4];
#pragma unroll
        for (int ot = 0; ot < 4; ++ot) bfrag[ot] = pbf[ot];

        // issue NEXT iteration's loads first (wrap on last iter — harmless re-read)
        int ktn = (kt + 1) & 63;
        int kbn = k0 + ktn * 32 + quad * 8;
        pt0 = *(const i32x4*)(tE12 + tb + kbn);
        pt1 = *(const i32x4*)(tE12 + tb + kbn + 4);
#pragma unroll
        for (int ot = 0; ot < 4; ++ot)
            pbf[ot] = *(const bf16x8*)(hB + ((w * 1024 + (kbn >> 3)) * 64 + ot * 16 + lx) * 8);

        // mask bytes from LDS (low latency, JIT)
        int mc[4];
#pragma unroll
        for (int r = 0; r < 4; ++r) mc[r] = smask[mrow[r] + kt * 4];

        // unpack packed table words ONCE (shared by all 4 r): e1 = lo16<<16, e2 = hi16
        float e1v[8], e2v[8];
#pragma unroll
        for (int c = 0; c < 8; ++c) {
            unsigned wd = (unsigned)((c < 4) ? t0[c] : t1[c - 4]);
            e1v[c] = __uint_as_float(wd << 16);
            e2v[c] = __uint_as_float(wd & 0xffff0000u);
        }

        // build P' (A-frags): p' = maskbit & max(E1j, Ri*E2j); truncate-pack to bf16
        bf16x8 afr[4];
#pragma unroll
        for (int r = 0; r < 4; ++r) {
            union { i32x4 i; bf16x8 b; } af;
#pragma unroll
            for (int jj = 0; jj < 4; ++jj) {   // two elements per iter -> packed bf16
                int j0 = 2 * jj, j1 = 2 * jj + 1;
                float p0 = fmaxf(e1v[j0], Riv[r] * e2v[j0]);  // = exp(leakyrelu(s))/exp(ei)
                float p1 = fmaxf(e1v[j1], Riv[r] * e2v[j1]);
                p0 = (mc[r] & (1 << j0)) ? p0 : 0.0f;         // adjacency mask bit
                p1 = (mc[r] & (1 << j1)) ? p1 : 0.0f;
                af.i[jj] = (int)__builtin_amdgcn_perm(__float_as_uint(p1),
                                                      __float_as_uint(p0),
                                                      0x07060302); // [p1.hi16|p0.hi16] trunc
            }
            afr[r] = af.b;
        }
#pragma unroll
        for (int r = 0; r < 4; ++r)            // row sums on the MFMA pipe (B = ones)
            accL[r] = __builtin_amdgcn_mfma_f32_16x16x32_bf16(afr[r], onesf, accL[r], 0, 0, 0);
#pragma unroll
        for (int r = 0; r < 4; ++r)
#pragma unroll
            for (int ot = 0; ot < 4; ++ot)
                acc[r][ot] = __builtin_amdgcn_mfma_f32_16x16x32_bf16(afr[r], bfrag[ot], acc[r][ot], 0, 0, 0);
    }

    // softmax denominators: accL[r][reg] holds rowsum(row=quad*4+reg) in every col lane
#pragma unroll
    for (int r = 0; r < 4; ++r)
        if (lx == 0)
#pragma unroll
            for (int reg = 0; reg < 4; ++reg)
                atomicAdd(&Lsum[w * NN + rowbase + r * 16 + quad * 4 + reg], accL[r][reg]);
    // numerator: atomic combine across the 4 K-splits
#pragma unroll
    for (int r = 0; r < 4; ++r)
#pragma unroll
        for (int ot = 0; ot < 4; ++ot)
#pragma unroll
            for (int reg = 0; reg < 4; ++reg) {
                int row = rowbase + r * 16 + quad * 4 + reg;    // C/D: row=quad*4+reg
                atomicAdd(&num[row * 256 + w * 64 + ot * 16 + lx], acc[r][ot][reg]);
            }
}

// ---------------- K3: BN partial stats only (no val write; k5 re-divides) ------------------
// grid 1024 blocks x 8 rows; thread t = column c (h*64+o)
__global__ __launch_bounds__(256) void k3_stats(const float* __restrict__ num,
                                                const float* __restrict__ Lsum,
                                                float* __restrict__ stats) {
    int c = threadIdx.x;
    int h = c >> 6;
    float s = 0.f, s2 = 0.f;
#pragma unroll
    for (int rr = 0; rr < 8; ++rr) {
        int row = blockIdx.x * 8 + rr;
        float val = num[row * 256 + c] / Lsum[h * NN + row];
        s += val; s2 += val * val;
    }
    atomicAdd(&stats[c], s);
    atomicAdd(&stats[c + 256], s2);
}

// ---------------- K5: BN finalize (LDS) + divide + apply + ReLU -> fp32 out ----------------
__global__ __launch_bounds__(256) void k5_apply(const float* __restrict__ num,
                                                const float* __restrict__ Lsum,
                                                const float* __restrict__ stats,
                                                const float* __restrict__ gamma,
                                                const float* __restrict__ beta,
                                                float* __restrict__ out) {
    __shared__ float sbnp[512];
    int c = threadIdx.x;
    float mean = stats[c] * (1.0f / NN);
    float var  = stats[c + 256] * (1.0f / NN) - mean * mean;
    float sc = gamma[c] * rsqrtf(var + BN_EPS);
    sbnp[c] = sc;
    sbnp[c + 256] = beta[c] - mean * sc;
    __syncthreads();

    int g = blockIdx.x * 256 + threadIdx.x;        // float4 index, 524288 total
    f32x4 v = *(const f32x4*)(num + (size_t)g * 4);
    int cb = (g * 4) & 255;
    int row = g >> 6;
    float rL = 1.0f / Lsum[(cb >> 6) * NN + row];
    f32x4 r;
#pragma unroll
    for (int j = 0; j < 4; ++j)
        r[j] = fmaxf((v[j] * rL) * sbnp[cb + j] + sbnp[256 + cb + j], 0.0f);
    *(f32x4*)(out + (size_t)g * 4) = r;
}

extern "C" void kernel_launch(void* const* d_in, const int* in_sizes, int n_in,
                              void* d_out, int out_size, void* d_ws, size_t ws_size,
                              hipStream_t stream) {
    (void)in_sizes; (void)n_in; (void)out_size; (void)ws_size;
    const float* x     = (const float*)d_in[0];
    const int*   adj   = (const int*)d_in[1];
    const float* W     = (const float*)d_in[2];
    const float* a_i   = (const float*)d_in[3];
    const float* a_j   = (const float*)d_in[4];
    const float* gamma = (const float*)d_in[5];
    const float* beta  = (const float*)d_in[6];
    float* out = (float*)d_out;

    char* ws = (char*)d_ws;
    // workspace layout (~13 MB). num|Lsum|stats contiguous -> single memset.
    short*        WB    = (short*)(ws + 0);           //   64 KB (bf16 W, B-frag layout)
    short*        hB    = (short*)(ws + 65536);       //    4 MB (bf16 h, B-frag layout)
    float*        t_Ri  = (float*)(ws + 4259840);     //  128 KB
    unsigned int* tE12  = (unsigned int*)(ws + 4390912);  // 128 KB packed [E2|E1] bf16
    float*        num   = (float*)(ws + 4521984);     //    8 MB (numerator, atomic-combined)
    float*        Lsum  = (float*)(ws + 12910592);    //  128 KB
    float*        stats = (float*)(ws + 13041664);    //    2 KB (atomic accum)

    hipMemsetAsync(num, 0, 8388608 + 131072 + 2048, stream);  // num + Lsum + stats

    k0_repackW<<<dim3(128),  dim3(256), 0, stream>>>(W, WB);
    k1_feat   <<<dim3(512),  dim3(256), 0, stream>>>(x, WB, a_i, a_j, hB, t_Ri, tE12);
    k2_attn   <<<dim3(512),  dim3(256), 0, stream>>>(adj, hB, t_Ri, tE12, num, Lsum);
    k3_stats  <<<dim3(1024), dim3(256), 0, stream>>>(num, Lsum, stats);
    k5_apply  <<<dim3(2048), dim3(256), 0, stream>>>(num, Lsum, stats, gamma, beta, out);
}